// Round 12
// baseline (210.885 us; speedup 1.0000x reference)
//
#include <hip/hip_runtime.h>
#include <hip/hip_fp16.h>
#include <math.h>

#define Cc 32
#define Hc 128
#define Wc 160
#define Dc 48
#define HWc (Hc*Wc)
#define TS 16
#define HALO (TS+2)           // 18
#define NPOS (HALO*HALO)      // 324
#define DCHUNK 3
#define NCHUNK (Dc/DCHUNK)    // 16
#define NPASS 6               // ceil(NPOS / 64 quads)
#define NTILE 80              // 10 x 8 spatial tiles

typedef _Float16 h2 __attribute__((ext_vector_type(2)));

static __device__ __forceinline__ float hdot2(h2 a, h2 b, float acc) {
#if __has_builtin(__builtin_amdgcn_fdot2)
    return __builtin_amdgcn_fdot2(a, b, acc, false);
#else
    return fmaf((float)a.y, (float)b.y, fmaf((float)a.x, (float)b.x, acc));
#endif
}

union F4H { float4 f; __half2 h[4]; h2 d[4]; };
union PackCW { __half2 h[4]; float4 f; };

// ---------------- kernel 1: transpose CHW->HWC (fp32->fp16) + proj + weights + zero ----------------
__global__ void k_pre(const float* __restrict__ f0, const float* __restrict__ f1,
                      const float* __restrict__ f2, const float* __restrict__ proj,
                      const float* __restrict__ wreg,
                      _Float16* __restrict__ o0, _Float16* __restrict__ o1, _Float16* __restrict__ o2,
                      float* __restrict__ wsproj, _Float16* __restrict__ w2h,
                      float* __restrict__ costvol, int* __restrict__ tileCnt) {
    const int tid = threadIdx.x;
    const int p = blockIdx.x * 256 + tid;
    if (blockIdx.y == 3) {
        // zero costvol + tile counters (ws is poisoned 0xAA each call)
        if (p < HWc) {
#pragma unroll
            for (int d = 0; d < Dc; d++) costvol[d * HWc + p] = 0.f;
        }
        if (p < NTILE) tileCnt[p] = 0;
        return;
    }
    if (p < HWc) {
        const float* f = (blockIdx.y == 0) ? f0 : (blockIdx.y == 1) ? f1 : f2;
        _Float16*    o = (blockIdx.y == 0) ? o0 : (blockIdx.y == 1) ? o1 : o2;
        float v[Cc];
#pragma unroll
        for (int c = 0; c < Cc; c++) v[c] = f[c * HWc + p];   // coalesced across lanes
        union { __half2 h[16]; float4 f4[4]; } rec;
#pragma unroll
        for (int c = 0; c < 16; c++) rec.h[c] = __floats2half2_rn(v[2 * c], v[2 * c + 1]);
        float4* o4 = (float4*)(o + (size_t)p * Cc);
#pragma unroll
        for (int j = 0; j < 4; j++) o4[j] = rec.f4[j];
    }
    if (blockIdx.x == 0 && blockIdx.y == 0) {
        // fp16 weight repack: w2h[khkw(9)][kd(3)][c(32)]
        for (int i = tid; i < 9 * 3 * Cc; i += 256) {
            int ch = i & 31;
            int t  = i >> 5;         // khkw*3 + kd
            int kd = t % 3;
            int khkw = t / 3;
            w2h[i] = (_Float16)wreg[ch * 27 + kd * 9 + khkw];
        }
        if (tid == 0) {
            float a[4][8];
            for (int i = 0; i < 4; i++)
                for (int j = 0; j < 4; j++) {
                    a[i][j]     = proj[i * 4 + j];
                    a[i][j + 4] = (i == j) ? 1.f : 0.f;
                }
            for (int col = 0; col < 4; col++) {
                int piv = col; float best = fabsf(a[col][col]);
                for (int r = col + 1; r < 4; r++) {
                    float v = fabsf(a[r][col]);
                    if (v > best) { best = v; piv = r; }
                }
                if (piv != col)
                    for (int j = 0; j < 8; j++) { float t = a[col][j]; a[col][j] = a[piv][j]; a[piv][j] = t; }
                float inv = 1.f / a[col][col];
                for (int j = 0; j < 8; j++) a[col][j] *= inv;
                for (int r = 0; r < 4; r++) if (r != col) {
                    float f = a[r][col];
                    for (int j = 0; j < 8; j++) a[r][j] -= f * a[col][j];
                }
            }
            for (int v = 1; v < 3; v++) {
                const float* P = proj + v * 16;
                float M[3][4];
                for (int i = 0; i < 3; i++)
                    for (int j = 0; j < 4; j++) {
                        float s = 0.f;
                        for (int k = 0; k < 4; k++) s += P[i * 4 + k] * a[k][4 + j];
                        M[i][j] = s;
                    }
                float* o = wsproj + (v - 1) * 12;
                o[0] = M[0][0]; o[1] = M[0][1]; o[2] = M[0][2];
                o[3] = M[1][0]; o[4] = M[1][1]; o[5] = M[1][2];
                o[6] = M[2][0]; o[7] = M[2][1]; o[8] = M[2][2];
                o[9] = M[0][3]; o[10] = M[1][3]; o[11] = M[2][3];
            }
        }
    }
}

// ---------------- kernel 2: fused warp + variance + 3D conv + fused softmax epilogue ----------------
// 256 thr, launch_bounds(256,2) (128-VGPR cap; only non-spilling config — R2/R6/R7).
// R12: (1) var_l pad dropped (4 planes of NPOS float4: conv reads consecutive-b128
// conflict-free; quad writes 2-way = free) -> LDS 31.2KB -> 5 blocks/CU, and
// 1280 blocks = 5*256 slots = exactly one generation at 20 waves/CU (R11's 36.9KB
// gave 4/CU -> 1.25 generations, 20%-fill tail). (2) k_softmax launch eliminated:
// last z-block per tile (agent-scope counter) softmaxes its 256 pixels, reading
// costvol via agent-scope atomic loads (coherent across XCDs). No spin -> no
// deadlock. Spill guard: WRITE_SIZE < 30MB.
__global__ __launch_bounds__(256, 2) void k_cost(
    const _Float16* __restrict__ fT0, const _Float16* __restrict__ fT1,
    const _Float16* __restrict__ fT2, const float* __restrict__ dvals,
    const float4* __restrict__ w2h4, const float* __restrict__ wsproj,
    const float* __restrict__ breg, float* __restrict__ costvol,
    int* __restrict__ tileCnt, float* __restrict__ out)
{
    __shared__ float4 var_l[NPOS * 4];       // 20736 B (4 channel-planes, no pad)
    __shared__ float4 parW[NPOS];            // 5184 B (fp16 cw pack)
    __shared__ float4 parI[NPOS];            // 5184 B (u16 idx pack)
    __shared__ float projl[24];
    __shared__ int lastFlag;

    const int tid = threadIdx.x;
    if (tid < 24) projl[tid] = wsproj[tid];
    __syncthreads();

    const int tileX = blockIdx.x;                 // 0..9
    const int tileY = blockIdx.y;                 // 0..7
    const int d0    = blockIdx.z * DCHUNK;
    const int tx = tid & 15, ty = tid >> 4;
    const int baseH = tileY * TS - 1, baseW = tileX * TS - 1;

    const int posq = tid >> 2;                    // quad id (0..63): position within pass
    const int cc   = tid & 3;                     // float4 slot within 32-ch fp16 record

    const float4* fT0_4 = (const float4*)fT0;
    const float4* fT1_4 = (const float4*)fT1;
    const float4* fT2_4 = (const float4*)fT2;

    // ---- Phase A setup: thread owns positions tid, tid+256; rays hoisted ----
    float rAx[2][2], rAy[2][2], rAz[2][2];
    float trn[2][3];
#pragma unroll
    for (int v = 0; v < 2; v++) {
        trn[v][0] = projl[v * 12 + 9];
        trn[v][1] = projl[v * 12 + 10];
        trn[v][2] = projl[v * 12 + 11];
    }
    int amask = 0;
#pragma unroll
    for (int s = 0; s < 2; s++) {
        int p = tid + s * 256;
        bool act = p < NPOS;
        int pp = act ? p : 0;
        int py = pp / HALO, px = pp % HALO;
        int hyi = baseH + py, hxi = baseW + px;
        bool ok = act && hyi >= 0 && hyi < Hc && hxi >= 0 && hxi < Wc;
        if (ok) amask |= (1 << s);
        float hx = (float)hxi, hy = (float)hyi;
#pragma unroll
        for (int v = 0; v < 2; v++) {
            const float* R = projl + v * 12;
            rAx[s][v] = fmaf(R[0], hx, fmaf(R[1], hy, R[2]));
            rAy[s][v] = fmaf(R[3], hx, fmaf(R[4], hy, R[5]));
            rAz[s][v] = fmaf(R[6], hx, fmaf(R[7], hy, R[8]));
        }
    }

    // ---- Phase B setup: per-pass validity + hoisted depth-independent ref taps ----
    int    bmask = 0;
    float4 rfv[NPASS];
#pragma unroll
    for (int s = 0; s < NPASS; s++) {
        int p = posq + s * 64;
        bool act = p < NPOS;
        int pp = act ? p : 0;
        int py = pp / HALO, px = pp % HALO;
        int hyi = baseH + py, hxi = baseW + px;
        bool ok = act && hyi >= 0 && hyi < Hc && hxi >= 0 && hxi < Wc;
        if (ok) bmask |= (1 << s);
        rfv[s] = ok ? fT0_4[(hyi * Wc + hxi) * 4 + cc] : make_float4(0.f, 0.f, 0.f, 0.f);
    }

    float cost[DCHUNK];
#pragma unroll
    for (int i = 0; i < DCHUNK; i++) cost[i] = 0.f;
    float bndLo = 0.f, bndHi = 0.f;               // contributions crossing chunk edges

    const int cb = ty * HALO + tx;                // conv center position

    // ---- Phase A: bilinear params for slice dpn -> parW/parI ----
    auto phaseA = [&](int dpn) {
        const float depthN = dvals[dpn];
#pragma unroll
        for (int s = 0; s < 2; s++) {
            int p = tid + s * 256;
            if (p >= NPOS) break;
            if (!((amask >> s) & 1)) continue;
            float cw[2][4]; unsigned int pk[4];
#pragma unroll
            for (int v = 0; v < 2; v++) {
                float X = fmaf(rAx[s][v], depthN, trn[v][0]);
                float Y = fmaf(rAy[s][v], depthN, trn[v][1]);
                float Z = fmaf(rAz[s][v], depthN, trn[v][2]);
                float iz = 1.f / Z;
                float gx = X * iz, gy = Y * iz;
                float x0f = floorf(gx), y0f = floorf(gy);
                float wx = gx - x0f, wy = gy - y0f;
                int x0 = (int)x0f, y0 = (int)y0f;
                bool vx0 = (x0 >= 0) & (x0 <= Wc - 1);
                bool vx1 = (x0 + 1 >= 0) & (x0 + 1 <= Wc - 1);
                bool vy0 = (y0 >= 0) & (y0 <= Hc - 1);
                bool vy1 = (y0 + 1 >= 0) & (y0 + 1 <= Hc - 1);
                int xc0 = min(max(x0, 0), Wc - 1), xc1 = min(max(x0 + 1, 0), Wc - 1);
                int yc0 = min(max(y0, 0), Hc - 1), yc1 = min(max(y0 + 1, 0), Hc - 1);
                float ax = 1.f - wx, ay = 1.f - wy;
                cw[v][0] = (vx0 && vy0) ? ax * ay : 0.f;
                cw[v][1] = (vx1 && vy0) ? wx * ay : 0.f;
                cw[v][2] = (vx0 && vy1) ? ax * wy : 0.f;
                cw[v][3] = (vx1 && vy1) ? wx * wy : 0.f;
                unsigned int i0 = (unsigned int)(yc0 * Wc + xc0);
                unsigned int i1 = (unsigned int)(yc0 * Wc + xc1);
                unsigned int i2 = (unsigned int)(yc1 * Wc + xc0);
                unsigned int i3 = (unsigned int)(yc1 * Wc + xc1);
                pk[v * 2 + 0] = i0 | (i1 << 16);
                pk[v * 2 + 1] = i2 | (i3 << 16);
            }
            PackCW pc;
            pc.h[0] = __floats2half2_rn(cw[0][0], cw[0][1]);
            pc.h[1] = __floats2half2_rn(cw[0][2], cw[0][3]);
            pc.h[2] = __floats2half2_rn(cw[1][0], cw[1][1]);
            pc.h[3] = __floats2half2_rn(cw[1][2], cw[1][3]);
            parW[p] = pc.f;
            parI[p] = make_float4(__uint_as_float(pk[0]), __uint_as_float(pk[1]),
                                  __uint_as_float(pk[2]), __uint_as_float(pk[3]));
        }
    };

    const int dpFirst = d0;
    const int dpLast  = d0 + DCHUNK - 1;          // no depth halo (atomic boundary adds)

    phaseA(dpFirst);
    __syncthreads();

    const __half2 kT3 = __float2half2_rn(1.f / 3.f);
    const __half2 kN9 = __float2half2_rn(-1.f / 9.f);

    for (int dp = dpFirst; dp <= dpLast; dp++) {
        // ---- Phase B: gather + variance -> var_l, all in packed fp16 ----
#pragma unroll
        for (int s = 0; s < NPASS; s++) {
            int p = posq + s * 64;
            if (p >= NPOS) continue;                 // only pass 5, posq>=4
            const int vaddr = cc * NPOS + p;
            if (!((bmask >> s) & 1)) {
                var_l[vaddr] = make_float4(0.f, 0.f, 0.f, 0.f);
                continue;
            }
            PackCW pc; pc.f = parW[p];               // quad-broadcast reads
            float4 pkf = parI[p];
            __half2 c0a = __low2half2(pc.h[0]), c0b = __high2half2(pc.h[0]);
            __half2 c0c = __low2half2(pc.h[1]), c0d = __high2half2(pc.h[1]);
            __half2 c1a = __low2half2(pc.h[2]), c1b = __high2half2(pc.h[2]);
            __half2 c1c = __low2half2(pc.h[3]), c1d = __high2half2(pc.h[3]);
            unsigned int u0 = __float_as_uint(pkf.x), u1 = __float_as_uint(pkf.y);
            unsigned int u2 = __float_as_uint(pkf.z), u3 = __float_as_uint(pkf.w);
            int i00 = u0 & 0xffff, i01 = u0 >> 16, i02 = u1 & 0xffff, i03 = u1 >> 16;
            int i10 = u2 & 0xffff, i11 = u2 >> 16, i12 = u3 & 0xffff, i13 = u3 >> 16;
            F4H rf; rf.f = rfv[s];
            F4H t00, t01, t10, t11, u00v, u01v, u10v, u11v, vo;
            t00.f = fT1_4[i00 * 4 + cc];
            t01.f = fT1_4[i01 * 4 + cc];
            t10.f = fT1_4[i02 * 4 + cc];
            t11.f = fT1_4[i03 * 4 + cc];
            u00v.f = fT2_4[i10 * 4 + cc];
            u01v.f = fT2_4[i11 * 4 + cc];
            u10v.f = fT2_4[i12 * 4 + cc];
            u11v.f = fT2_4[i13 * 4 + cc];
#pragma unroll
            for (int j = 0; j < 4; j++) {
                __half2 a1 = __hfma2(c0a, t00.h[j], __hfma2(c0b, t01.h[j],
                             __hfma2(c0c, t10.h[j], __hmul2(c0d, t11.h[j]))));
                __half2 a2 = __hfma2(c1a, u00v.h[j], __hfma2(c1b, u01v.h[j],
                             __hfma2(c1c, u10v.h[j], __hmul2(c1d, u11v.h[j]))));
                __half2 r  = rf.h[j];
                __half2 sm = __hadd2(r, __hadd2(a1, a2));
                __half2 sq = __hfma2(r, r, __hfma2(a1, a1, __hmul2(a2, a2)));
                vo.h[j] = __hfma2(__hmul2(sm, sm), kN9, __hmul2(sq, kT3));
            }
            var_l[vaddr] = vo.f;
        }
        __syncthreads();

        // ---- Phase A for next slice (overlaps conv latency) ----
        if (dp < dpLast) phaseA(dp + 1);

        // ---- 3x3 spatial conv via fp16 dot2: 3 kd planes, 32 channels ----
        float a0 = 0.f, a1 = 0.f, a2 = 0.f;
#pragma unroll
        for (int k = 0; k < 9; k++) {
            const int vpPos = cb + (k / 3) * HALO + (k % 3);
            F4H va[4];
#pragma unroll
            for (int j = 0; j < 4; j++) va[j].f = var_l[j * NPOS + vpPos];
            const int wb = k * 12;                   // float4 units: (k*3+kd)*4
#pragma unroll
            for (int j = 0; j < 4; j++) {
                F4H w0, w1, w2v;
                w0.f  = w2h4[wb + 0 + j];
                w1.f  = w2h4[wb + 4 + j];
                w2v.f = w2h4[wb + 8 + j];
#pragma unroll
                for (int i = 0; i < 4; i++) {
                    a0 = hdot2(va[j].d[i], w0.d[i], a0);
                    a1 = hdot2(va[j].d[i], w1.d[i], a1);
                    a2 = hdot2(va[j].d[i], w2v.d[i], a2);
                }
            }
        }
        // contributions: a0 -> cost[dp+1], a1 -> cost[dp], a2 -> cost[dp-1]
        cost[dp - d0] += a1;
        int r0 = dp + 1 - d0;
        if (r0 < DCHUNK) cost[r0] += a0; else bndHi = a0;
        int r2 = dp - 1 - d0;
        if (r2 >= 0) cost[r2] += a2; else bndLo = a2;
        __syncthreads();
    }

    // ---- accumulate into global costvol (pre-zeroed; neighbors also add) ----
    const int h = tileY * TS + ty, w = tileX * TS + tx;
    const int px = h * Wc + w;
    float* base = costvol + px;
#pragma unroll
    for (int i = 0; i < DCHUNK; i++)
        atomicAdd(base + (size_t)(d0 + i) * HWc, cost[i]);
    if (d0 > 0)            atomicAdd(base + (size_t)(d0 - 1) * HWc, bndLo);
    if (d0 + DCHUNK < Dc)  atomicAdd(base + (size_t)(d0 + DCHUNK) * HWc, bndHi);

    // ---- fused softmax epilogue: last z-block of this tile does the reduction ----
    __threadfence();                              // drain atomics to coherent point
    __syncthreads();
    if (tid == 0) {
        int prev = __hip_atomic_fetch_add(&tileCnt[tileY * 10 + tileX], 1,
                                          __ATOMIC_ACQ_REL, __HIP_MEMORY_SCOPE_AGENT);
        lastFlag = (prev == NCHUNK - 1) ? 1 : 0;
    }
    __syncthreads();
    if (lastFlag) {
        const float bias = breg[0];
        float c[Dc];
        float m = -1e30f;
#pragma unroll
        for (int d = 0; d < Dc; d++) {
            float v = __hip_atomic_load(costvol + (size_t)d * HWc + px,
                                        __ATOMIC_RELAXED, __HIP_MEMORY_SCOPE_AGENT);
            c[d] = v + bias;
            m = fmaxf(m, c[d]);
        }
        float se = 0.f, sed = 0.f, me = 0.f;
#pragma unroll
        for (int d = 0; d < Dc; d++) {
            float e = __expf(c[d] - m);
            se += e;
            sed = fmaf(e, dvals[d], sed);
            me = fmaxf(me, e);
        }
        float inv = 1.f / se;
        out[px]       = sed * inv;   // depth
        out[HWc + px] = me * inv;    // photometric confidence
    }
}

extern "C" void kernel_launch(void* const* d_in, const int* in_sizes, int n_in,
                              void* d_out, int out_size, void* d_ws, size_t ws_size,
                              hipStream_t stream) {
    const float* f0    = (const float*)d_in[0];
    const float* f1    = (const float*)d_in[1];
    const float* f2    = (const float*)d_in[2];
    const float* proj  = (const float*)d_in[3];
    const float* dvals = (const float*)d_in[4];
    const float* wreg  = (const float*)d_in[5];
    const float* breg  = (const float*)d_in[6];

    float* ws      = (float*)d_ws;
    float* wsproj  = ws;                         // 24 floats (pad to 32)
    _Float16* w2h  = (_Float16*)(ws + 32);       // 864 fp16 = 432 float slots
    _Float16* fT0h = (_Float16*)(ws + 32 + 432); // HWc*32 fp16 = 1.31MB each
    _Float16* fT1h = fT0h + (size_t)HWc * Cc;
    _Float16* fT2h = fT1h + (size_t)HWc * Cc;
    float* costvol = (float*)(fT2h + (size_t)HWc * Cc);  // Dc*HWc floats
    int*   tileCnt = (int*)(costvol + (size_t)Dc * HWc); // 80 ints

    k_pre<<<dim3((HWc + 255) / 256, 4), 256, 0, stream>>>(f0, f1, f2, proj, wreg,
                                                          fT0h, fT1h, fT2h, wsproj, w2h,
                                                          costvol, tileCnt);

    dim3 grid(Wc / TS, Hc / TS, NCHUNK);   // 10 x 8 x 16 = 1280 blocks of 256
    k_cost<<<grid, 256, 0, stream>>>(fT0h, fT1h, fT2h, dvals, (const float4*)w2h,
                                     wsproj, breg, costvol, tileCnt, (float*)d_out);
}

// Round 13
// 137.489 us; speedup vs baseline: 1.5338x; 1.5338x over previous
//
#include <hip/hip_runtime.h>
#include <hip/hip_fp16.h>
#include <math.h>

#define Cc 32
#define Hc 128
#define Wc 160
#define Dc 48
#define HWc (Hc*Wc)
#define TS 16
#define HALO (TS+2)           // 18
#define NPOS (HALO*HALO)      // 324
#define DCHUNK 3
#define NCHUNK (Dc/DCHUNK)    // 16
#define NPASS 6               // ceil(NPOS / 64 quads)

typedef _Float16 h2 __attribute__((ext_vector_type(2)));

static __device__ __forceinline__ float hdot2(h2 a, h2 b, float acc) {
#if __has_builtin(__builtin_amdgcn_fdot2)
    return __builtin_amdgcn_fdot2(a, b, acc, false);
#else
    return fmaf((float)a.y, (float)b.y, fmaf((float)a.x, (float)b.x, acc));
#endif
}

union F4H { float4 f; __half2 h[4]; h2 d[4]; };
union PackCW { __half2 h[4]; float4 f; };

// ---------------- kernel 1: transpose CHW->HWC (fp32->fp16) + proj + weights + costvol zero ----------------
__global__ void k_pre(const float* __restrict__ f0, const float* __restrict__ f1,
                      const float* __restrict__ f2, const float* __restrict__ proj,
                      const float* __restrict__ wreg,
                      _Float16* __restrict__ o0, _Float16* __restrict__ o1, _Float16* __restrict__ o2,
                      float* __restrict__ wsproj, _Float16* __restrict__ w2h,
                      float* __restrict__ costvol) {
    const int tid = threadIdx.x;
    const int p = blockIdx.x * 256 + tid;
    if (blockIdx.y == 3) {
        // zero costvol for atomic accumulation (ws is poisoned 0xAA each call)
        if (p < HWc) {
#pragma unroll
            for (int d = 0; d < Dc; d++) costvol[d * HWc + p] = 0.f;
        }
        return;
    }
    if (p < HWc) {
        const float* f = (blockIdx.y == 0) ? f0 : (blockIdx.y == 1) ? f1 : f2;
        _Float16*    o = (blockIdx.y == 0) ? o0 : (blockIdx.y == 1) ? o1 : o2;
        float v[Cc];
#pragma unroll
        for (int c = 0; c < Cc; c++) v[c] = f[c * HWc + p];   // coalesced across lanes
        union { __half2 h[16]; float4 f4[4]; } rec;
#pragma unroll
        for (int c = 0; c < 16; c++) rec.h[c] = __floats2half2_rn(v[2 * c], v[2 * c + 1]);
        float4* o4 = (float4*)(o + (size_t)p * Cc);
#pragma unroll
        for (int j = 0; j < 4; j++) o4[j] = rec.f4[j];
    }
    if (blockIdx.x == 0 && blockIdx.y == 0) {
        // fp16 weight repack: w2h[khkw(9)][kd(3)][c(32)]
        for (int i = tid; i < 9 * 3 * Cc; i += 256) {
            int ch = i & 31;
            int t  = i >> 5;         // khkw*3 + kd
            int kd = t % 3;
            int khkw = t / 3;
            w2h[i] = (_Float16)wreg[ch * 27 + kd * 9 + khkw];
        }
        if (tid == 0) {
            float a[4][8];
            for (int i = 0; i < 4; i++)
                for (int j = 0; j < 4; j++) {
                    a[i][j]     = proj[i * 4 + j];
                    a[i][j + 4] = (i == j) ? 1.f : 0.f;
                }
            for (int col = 0; col < 4; col++) {
                int piv = col; float best = fabsf(a[col][col]);
                for (int r = col + 1; r < 4; r++) {
                    float v = fabsf(a[r][col]);
                    if (v > best) { best = v; piv = r; }
                }
                if (piv != col)
                    for (int j = 0; j < 8; j++) { float t = a[col][j]; a[col][j] = a[piv][j]; a[piv][j] = t; }
                float inv = 1.f / a[col][col];
                for (int j = 0; j < 8; j++) a[col][j] *= inv;
                for (int r = 0; r < 4; r++) if (r != col) {
                    float f = a[r][col];
                    for (int j = 0; j < 8; j++) a[r][j] -= f * a[col][j];
                }
            }
            for (int v = 1; v < 3; v++) {
                const float* P = proj + v * 16;
                float M[3][4];
                for (int i = 0; i < 3; i++)
                    for (int j = 0; j < 4; j++) {
                        float s = 0.f;
                        for (int k = 0; k < 4; k++) s += P[i * 4 + k] * a[k][4 + j];
                        M[i][j] = s;
                    }
                float* o = wsproj + (v - 1) * 12;
                o[0] = M[0][0]; o[1] = M[0][1]; o[2] = M[0][2];
                o[3] = M[1][0]; o[4] = M[1][1]; o[5] = M[1][2];
                o[6] = M[2][0]; o[7] = M[2][1]; o[8] = M[2][2];
                o[9] = M[0][3]; o[10] = M[1][3]; o[11] = M[2][3];
            }
        }
    }
}

// ---------------- kernel 2: fused warp + variance + 3D conv, no depth halo ----------------
// 256 thr, launch_bounds(256,2) (128-VGPR cap; only non-spilling config — R2/R6/R7).
// R13 = R11 + R12's var_l relayout ONLY (4 planes of NPOS float4, no pad:
// conv reads consecutive-b128 conflict-free, quad writes 2-way = free) ->
// LDS 31.2KB -> 5 blocks/CU -> 1280 blocks = 5*256 = EXACTLY one generation
// at 20 waves/CU (R11: 4/CU -> 1.25 generations, 20%-fill tail).
// R12's fused softmax epilogue REVERTED: per-block __threadfence (device-scope
// L2 drain x1280) + coherent loads cost +61us (141 vs 80) — worse than the
// ~25us launch it saved. Spill guard: WRITE_SIZE < 30MB.
__global__ __launch_bounds__(256, 2) void k_cost(
    const _Float16* __restrict__ fT0, const _Float16* __restrict__ fT1,
    const _Float16* __restrict__ fT2, const float* __restrict__ dvals,
    const float4* __restrict__ w2h4, const float* __restrict__ wsproj,
    float* __restrict__ costvol)
{
    __shared__ float4 var_l[NPOS * 4];       // 20736 B (4 channel-planes, no pad)
    __shared__ float4 parW[NPOS];            // 5184 B (fp16 cw pack)
    __shared__ float4 parI[NPOS];            // 5184 B (u16 idx pack)
    __shared__ float projl[24];

    const int tid = threadIdx.x;
    if (tid < 24) projl[tid] = wsproj[tid];
    __syncthreads();

    const int tileX = blockIdx.x;                 // 0..9
    const int tileY = blockIdx.y;                 // 0..7
    const int d0    = blockIdx.z * DCHUNK;
    const int tx = tid & 15, ty = tid >> 4;
    const int baseH = tileY * TS - 1, baseW = tileX * TS - 1;

    const int posq = tid >> 2;                    // quad id (0..63): position within pass
    const int cc   = tid & 3;                     // float4 slot within 32-ch fp16 record

    const float4* fT0_4 = (const float4*)fT0;
    const float4* fT1_4 = (const float4*)fT1;
    const float4* fT2_4 = (const float4*)fT2;

    // ---- Phase A setup: thread owns positions tid, tid+256; rays hoisted ----
    float rAx[2][2], rAy[2][2], rAz[2][2];
    float trn[2][3];
#pragma unroll
    for (int v = 0; v < 2; v++) {
        trn[v][0] = projl[v * 12 + 9];
        trn[v][1] = projl[v * 12 + 10];
        trn[v][2] = projl[v * 12 + 11];
    }
    int amask = 0;
#pragma unroll
    for (int s = 0; s < 2; s++) {
        int p = tid + s * 256;
        bool act = p < NPOS;
        int pp = act ? p : 0;
        int py = pp / HALO, px = pp % HALO;
        int hyi = baseH + py, hxi = baseW + px;
        bool ok = act && hyi >= 0 && hyi < Hc && hxi >= 0 && hxi < Wc;
        if (ok) amask |= (1 << s);
        float hx = (float)hxi, hy = (float)hyi;
#pragma unroll
        for (int v = 0; v < 2; v++) {
            const float* R = projl + v * 12;
            rAx[s][v] = fmaf(R[0], hx, fmaf(R[1], hy, R[2]));
            rAy[s][v] = fmaf(R[3], hx, fmaf(R[4], hy, R[5]));
            rAz[s][v] = fmaf(R[6], hx, fmaf(R[7], hy, R[8]));
        }
    }

    // ---- Phase B setup: per-pass validity + hoisted depth-independent ref taps ----
    int    bmask = 0;
    float4 rfv[NPASS];
#pragma unroll
    for (int s = 0; s < NPASS; s++) {
        int p = posq + s * 64;
        bool act = p < NPOS;
        int pp = act ? p : 0;
        int py = pp / HALO, px = pp % HALO;
        int hyi = baseH + py, hxi = baseW + px;
        bool ok = act && hyi >= 0 && hyi < Hc && hxi >= 0 && hxi < Wc;
        if (ok) bmask |= (1 << s);
        rfv[s] = ok ? fT0_4[(hyi * Wc + hxi) * 4 + cc] : make_float4(0.f, 0.f, 0.f, 0.f);
    }

    float cost[DCHUNK];
#pragma unroll
    for (int i = 0; i < DCHUNK; i++) cost[i] = 0.f;
    float bndLo = 0.f, bndHi = 0.f;               // contributions crossing chunk edges

    const int cb = ty * HALO + tx;                // conv center position

    // ---- Phase A: bilinear params for slice dpn -> parW/parI ----
    auto phaseA = [&](int dpn) {
        const float depthN = dvals[dpn];
#pragma unroll
        for (int s = 0; s < 2; s++) {
            int p = tid + s * 256;
            if (p >= NPOS) break;
            if (!((amask >> s) & 1)) continue;
            float cw[2][4]; unsigned int pk[4];
#pragma unroll
            for (int v = 0; v < 2; v++) {
                float X = fmaf(rAx[s][v], depthN, trn[v][0]);
                float Y = fmaf(rAy[s][v], depthN, trn[v][1]);
                float Z = fmaf(rAz[s][v], depthN, trn[v][2]);
                float iz = 1.f / Z;
                float gx = X * iz, gy = Y * iz;
                float x0f = floorf(gx), y0f = floorf(gy);
                float wx = gx - x0f, wy = gy - y0f;
                int x0 = (int)x0f, y0 = (int)y0f;
                bool vx0 = (x0 >= 0) & (x0 <= Wc - 1);
                bool vx1 = (x0 + 1 >= 0) & (x0 + 1 <= Wc - 1);
                bool vy0 = (y0 >= 0) & (y0 <= Hc - 1);
                bool vy1 = (y0 + 1 >= 0) & (y0 + 1 <= Hc - 1);
                int xc0 = min(max(x0, 0), Wc - 1), xc1 = min(max(x0 + 1, 0), Wc - 1);
                int yc0 = min(max(y0, 0), Hc - 1), yc1 = min(max(y0 + 1, 0), Hc - 1);
                float ax = 1.f - wx, ay = 1.f - wy;
                cw[v][0] = (vx0 && vy0) ? ax * ay : 0.f;
                cw[v][1] = (vx1 && vy0) ? wx * ay : 0.f;
                cw[v][2] = (vx0 && vy1) ? ax * wy : 0.f;
                cw[v][3] = (vx1 && vy1) ? wx * wy : 0.f;
                unsigned int i0 = (unsigned int)(yc0 * Wc + xc0);
                unsigned int i1 = (unsigned int)(yc0 * Wc + xc1);
                unsigned int i2 = (unsigned int)(yc1 * Wc + xc0);
                unsigned int i3 = (unsigned int)(yc1 * Wc + xc1);
                pk[v * 2 + 0] = i0 | (i1 << 16);
                pk[v * 2 + 1] = i2 | (i3 << 16);
            }
            PackCW pc;
            pc.h[0] = __floats2half2_rn(cw[0][0], cw[0][1]);
            pc.h[1] = __floats2half2_rn(cw[0][2], cw[0][3]);
            pc.h[2] = __floats2half2_rn(cw[1][0], cw[1][1]);
            pc.h[3] = __floats2half2_rn(cw[1][2], cw[1][3]);
            parW[p] = pc.f;
            parI[p] = make_float4(__uint_as_float(pk[0]), __uint_as_float(pk[1]),
                                  __uint_as_float(pk[2]), __uint_as_float(pk[3]));
        }
    };

    const int dpFirst = d0;
    const int dpLast  = d0 + DCHUNK - 1;          // no depth halo (atomic boundary adds)

    phaseA(dpFirst);
    __syncthreads();

    const __half2 kT3 = __float2half2_rn(1.f / 3.f);
    const __half2 kN9 = __float2half2_rn(-1.f / 9.f);

    for (int dp = dpFirst; dp <= dpLast; dp++) {
        // ---- Phase B: gather + variance -> var_l, all in packed fp16 ----
#pragma unroll
        for (int s = 0; s < NPASS; s++) {
            int p = posq + s * 64;
            if (p >= NPOS) continue;                 // only pass 5, posq>=4
            const int vaddr = cc * NPOS + p;
            if (!((bmask >> s) & 1)) {
                var_l[vaddr] = make_float4(0.f, 0.f, 0.f, 0.f);
                continue;
            }
            PackCW pc; pc.f = parW[p];               // quad-broadcast reads
            float4 pkf = parI[p];
            __half2 c0a = __low2half2(pc.h[0]), c0b = __high2half2(pc.h[0]);
            __half2 c0c = __low2half2(pc.h[1]), c0d = __high2half2(pc.h[1]);
            __half2 c1a = __low2half2(pc.h[2]), c1b = __high2half2(pc.h[2]);
            __half2 c1c = __low2half2(pc.h[3]), c1d = __high2half2(pc.h[3]);
            unsigned int u0 = __float_as_uint(pkf.x), u1 = __float_as_uint(pkf.y);
            unsigned int u2 = __float_as_uint(pkf.z), u3 = __float_as_uint(pkf.w);
            int i00 = u0 & 0xffff, i01 = u0 >> 16, i02 = u1 & 0xffff, i03 = u1 >> 16;
            int i10 = u2 & 0xffff, i11 = u2 >> 16, i12 = u3 & 0xffff, i13 = u3 >> 16;
            F4H rf; rf.f = rfv[s];
            F4H t00, t01, t10, t11, u00v, u01v, u10v, u11v, vo;
            t00.f = fT1_4[i00 * 4 + cc];
            t01.f = fT1_4[i01 * 4 + cc];
            t10.f = fT1_4[i02 * 4 + cc];
            t11.f = fT1_4[i03 * 4 + cc];
            u00v.f = fT2_4[i10 * 4 + cc];
            u01v.f = fT2_4[i11 * 4 + cc];
            u10v.f = fT2_4[i12 * 4 + cc];
            u11v.f = fT2_4[i13 * 4 + cc];
#pragma unroll
            for (int j = 0; j < 4; j++) {
                __half2 a1 = __hfma2(c0a, t00.h[j], __hfma2(c0b, t01.h[j],
                             __hfma2(c0c, t10.h[j], __hmul2(c0d, t11.h[j]))));
                __half2 a2 = __hfma2(c1a, u00v.h[j], __hfma2(c1b, u01v.h[j],
                             __hfma2(c1c, u10v.h[j], __hmul2(c1d, u11v.h[j]))));
                __half2 r  = rf.h[j];
                __half2 sm = __hadd2(r, __hadd2(a1, a2));
                __half2 sq = __hfma2(r, r, __hfma2(a1, a1, __hmul2(a2, a2)));
                vo.h[j] = __hfma2(__hmul2(sm, sm), kN9, __hmul2(sq, kT3));
            }
            var_l[vaddr] = vo.f;
        }
        __syncthreads();

        // ---- Phase A for next slice (overlaps conv latency) ----
        if (dp < dpLast) phaseA(dp + 1);

        // ---- 3x3 spatial conv via fp16 dot2: 3 kd planes, 32 channels ----
        float a0 = 0.f, a1 = 0.f, a2 = 0.f;
#pragma unroll
        for (int k = 0; k < 9; k++) {
            const int vpPos = cb + (k / 3) * HALO + (k % 3);
            F4H va[4];
#pragma unroll
            for (int j = 0; j < 4; j++) va[j].f = var_l[j * NPOS + vpPos];
            const int wb = k * 12;                   // float4 units: (k*3+kd)*4
#pragma unroll
            for (int j = 0; j < 4; j++) {
                F4H w0, w1, w2v;
                w0.f  = w2h4[wb + 0 + j];
                w1.f  = w2h4[wb + 4 + j];
                w2v.f = w2h4[wb + 8 + j];
#pragma unroll
                for (int i = 0; i < 4; i++) {
                    a0 = hdot2(va[j].d[i], w0.d[i], a0);
                    a1 = hdot2(va[j].d[i], w1.d[i], a1);
                    a2 = hdot2(va[j].d[i], w2v.d[i], a2);
                }
            }
        }
        // contributions: a0 -> cost[dp+1], a1 -> cost[dp], a2 -> cost[dp-1]
        cost[dp - d0] += a1;
        int r0 = dp + 1 - d0;
        if (r0 < DCHUNK) cost[r0] += a0; else bndHi = a0;
        int r2 = dp - 1 - d0;
        if (r2 >= 0) cost[r2] += a2; else bndLo = a2;
        __syncthreads();
    }

    // ---- accumulate into global costvol (pre-zeroed; neighbors also add) ----
    const int h = tileY * TS + ty, w = tileX * TS + tx;
    float* base = costvol + h * Wc + w;
#pragma unroll
    for (int i = 0; i < DCHUNK; i++)
        atomicAdd(base + (size_t)(d0 + i) * HWc, cost[i]);
    if (d0 > 0)            atomicAdd(base + (size_t)(d0 - 1) * HWc, bndLo);
    if (d0 + DCHUNK < Dc)  atomicAdd(base + (size_t)(d0 + DCHUNK) * HWc, bndHi);
}

// ---------------- kernel 3: softmax over depth + regression ----------------
__global__ void k_softmax(const float* __restrict__ costvol, const float* __restrict__ dvals,
                          const float* __restrict__ breg, float* __restrict__ out)
{
    const int px = blockIdx.x * 256 + threadIdx.x;
    if (px >= HWc) return;
    const float bias = breg[0];
    float c[Dc];
    float m = -1e30f;
#pragma unroll
    for (int d = 0; d < Dc; d++) {
        c[d] = costvol[d * HWc + px] + bias;
        m = fmaxf(m, c[d]);
    }
    float se = 0.f, sed = 0.f, me = 0.f;
#pragma unroll
    for (int d = 0; d < Dc; d++) {
        float e = __expf(c[d] - m);
        se += e;
        sed = fmaf(e, dvals[d], sed);
        me = fmaxf(me, e);
    }
    float inv = 1.f / se;
    out[px]       = sed * inv;   // depth
    out[HWc + px] = me * inv;    // photometric confidence
}

extern "C" void kernel_launch(void* const* d_in, const int* in_sizes, int n_in,
                              void* d_out, int out_size, void* d_ws, size_t ws_size,
                              hipStream_t stream) {
    const float* f0    = (const float*)d_in[0];
    const float* f1    = (const float*)d_in[1];
    const float* f2    = (const float*)d_in[2];
    const float* proj  = (const float*)d_in[3];
    const float* dvals = (const float*)d_in[4];
    const float* wreg  = (const float*)d_in[5];
    const float* breg  = (const float*)d_in[6];

    float* ws      = (float*)d_ws;
    float* wsproj  = ws;                         // 24 floats (pad to 32)
    _Float16* w2h  = (_Float16*)(ws + 32);       // 864 fp16 = 432 float slots
    _Float16* fT0h = (_Float16*)(ws + 32 + 432); // HWc*32 fp16 = 1.31MB each
    _Float16* fT1h = fT0h + (size_t)HWc * Cc;
    _Float16* fT2h = fT1h + (size_t)HWc * Cc;
    float* costvol = (float*)(fT2h + (size_t)HWc * Cc);  // Dc*HWc floats

    k_pre<<<dim3((HWc + 255) / 256, 4), 256, 0, stream>>>(f0, f1, f2, proj, wreg,
                                                          fT0h, fT1h, fT2h, wsproj, w2h,
                                                          costvol);

    dim3 grid(Wc / TS, Hc / TS, NCHUNK);   // 10 x 8 x 16 = 1280 blocks of 256
    k_cost<<<grid, 256, 0, stream>>>(fT0h, fT1h, fT2h, dvals, (const float4*)w2h,
                                     wsproj, costvol);

    k_softmax<<<(HWc + 255) / 256, 256, 0, stream>>>(costvol, dvals, breg, (float*)d_out);
}